// Round 2
// baseline (8441.323 us; speedup 1.0000x reference)
//
#include <hip/hip_runtime.h>
#include <math.h>

#define B_    128
#define T_ENC 40
#define T_DEC 27
#define HID_  512
#define G3_   1536
#define EMB_  1024
#define V_    20000
#define KC    32
#define NBLK  256

__device__ __forceinline__ float sigmoidf_(float x) { return 1.f / (1.f + expf(-x)); }

// ---------------- device-scope grid barrier (all NBLK blocks co-resident: 1024 waves << 8192 cap) ----
__device__ __forceinline__ void grid_barrier(unsigned* cnt, unsigned* gen) {
  __syncthreads();
  if (threadIdx.x == 0) {
    __threadfence();  // release: our writes visible at device scope
    unsigned g0 = __hip_atomic_load(gen, __ATOMIC_RELAXED, __HIP_MEMORY_SCOPE_AGENT);
    if (atomicAdd(cnt, 1u) == NBLK - 1u) {
      __hip_atomic_store(cnt, 0u, __ATOMIC_RELAXED, __HIP_MEMORY_SCOPE_AGENT);
      __hip_atomic_store(gen, g0 + 1u, __ATOMIC_RELEASE, __HIP_MEMORY_SCOPE_AGENT);
    } else {
      while (__hip_atomic_load(gen, __ATOMIC_ACQUIRE, __HIP_MEMORY_SCOPE_AGENT) == g0) {
        __builtin_amdgcn_s_sleep(2);
      }
    }
    __threadfence();  // acquire: invalidate stale L1/L2 before the block reads others' data
  }
  __syncthreads();
}

// ---------------- gather decoder word embeddings ----------------
__global__ __launch_bounds__(128) void k_gather(const int* __restrict__ target,
                                                const float* __restrict__ E,
                                                float* __restrict__ words) {
  int m = blockIdx.x;
  int b = m / T_DEC, t = m % T_DEC;
  int idx = target[b * 28 + t];
  const float4* src = reinterpret_cast<const float4*>(E + (size_t)idx * HID_);
  float4* dst = reinterpret_cast<float4*>(words + (size_t)m * HID_);
  dst[threadIdx.x] = src[threadIdx.x];
}

// ---------------- generic fp32 GEMM (unchanged from round 1; passed) ----------------
__global__ __launch_bounds__(256) void k_gemm(const float* __restrict__ A, int lda,
                                              const float* __restrict__ Bm, int ldb, int boff,
                                              const float* __restrict__ bias,
                                              float* __restrict__ C, int ldc,
                                              int N, int K) {
  __shared__ float As[16][128];
  __shared__ float Bs[16][128];
  const int tid = threadIdx.x;
  const int m0 = blockIdx.y * 128;
  const int n0 = blockIdx.x * 128;
  const int tx = tid & 15, ty = tid >> 4;
  float acc[8][8];
#pragma unroll
  for (int i = 0; i < 8; ++i)
#pragma unroll
    for (int j = 0; j < 8; ++j) acc[i][j] = 0.f;

  for (int k0 = 0; k0 < K; k0 += 16) {
#pragma unroll
    for (int i = 0; i < 2; ++i) {
      int v = tid * 2 + i;
      int row = v >> 2;
      int kv = (v & 3) << 2;
      float4 a4 = *reinterpret_cast<const float4*>(&A[(size_t)(m0 + row) * lda + k0 + kv]);
      As[kv + 0][row] = a4.x; As[kv + 1][row] = a4.y; As[kv + 2][row] = a4.z; As[kv + 3][row] = a4.w;
      int nr = n0 + row;
      float4 b4 = make_float4(0.f, 0.f, 0.f, 0.f);
      if (nr < N) b4 = *reinterpret_cast<const float4*>(&Bm[(size_t)nr * ldb + boff + k0 + kv]);
      Bs[kv + 0][row] = b4.x; Bs[kv + 1][row] = b4.y; Bs[kv + 2][row] = b4.z; Bs[kv + 3][row] = b4.w;
    }
    __syncthreads();
#pragma unroll
    for (int kk = 0; kk < 16; ++kk) {
      float a[8], bb[8];
      *reinterpret_cast<float4*>(&a[0]) = *reinterpret_cast<const float4*>(&As[kk][ty * 8]);
      *reinterpret_cast<float4*>(&a[4]) = *reinterpret_cast<const float4*>(&As[kk][ty * 8 + 4]);
      *reinterpret_cast<float4*>(&bb[0]) = *reinterpret_cast<const float4*>(&Bs[kk][tx * 8]);
      *reinterpret_cast<float4*>(&bb[4]) = *reinterpret_cast<const float4*>(&Bs[kk][tx * 8 + 4]);
#pragma unroll
      for (int i = 0; i < 8; ++i)
#pragma unroll
        for (int j = 0; j < 8; ++j) acc[i][j] += a[i] * bb[j];
    }
    __syncthreads();
  }
#pragma unroll
  for (int i = 0; i < 8; ++i) {
    int m = m0 + ty * 8 + i;
    int n = n0 + tx * 8;
    if (n < N) {
      float* cp = &C[(size_t)m * ldc + n];
#pragma unroll
      for (int j = 0; j < 8; ++j) cp[j] = acc[i][j] + bias[n + j];
    }
  }
}

// ---------------- persistent recurrence kernel: all 67 steps, 2 grid barriers/step ----------------
// Phase A: blocks 0..127: gh1 = h1_old@W_hh1^T, combine -> h1_new (block owns 4 units x 3 gates)
//          blocks 128..255: gh2 = h2_old@W_hh2^T + b_hh2 (12 linear cols/block)
// Phase B: all blocks: gi2 = h1_new@W_ih2[:,:512]^T, combine with gh2 -> h2_new (2 units/block)
__global__ __launch_bounds__(256) void k_recur(
    const float* __restrict__ G1, const float* __restrict__ GW,
    const float* __restrict__ W_hh1, const float* __restrict__ b_hh1,
    const float* __restrict__ W_hh2, const float* __restrict__ b_hh2,
    const float* __restrict__ W_ih2, const float* __restrict__ b_ih1,
    const float* __restrict__ b_ih2,
    float* h1a, float* h1b, float* h2a, float* h2b,
    float* __restrict__ gh2, float* __restrict__ h2seq,
    unsigned* bar_cnt, unsigned* bar_gen) {
  const int bid = blockIdx.x;
  const int tid = threadIdx.x;
  __shared__ float Hs[KC][132];   // [k][b], padded: conflict-light reads
  __shared__ float Ws[KC][20];    // [k][u*4+g], padded for b128 reads

  float* h1r = h1a; float* h1w = h1b;
  float* h2r = h2a; float* h2w = h2b;

  const bool isL1 = bid < 128;
  const int u0A = isL1 ? bid * 4 : 0;          // L1: 4 units per block
  const int c0A = isL1 ? 0 : (bid - 128) * 12; // L2: 12 linear cols per block
  const float* WA = isL1 ? W_hh1 : W_hh2;
  const int txu = tid & 3;   // phase A: unit (L1) / col-triple (L2)
  const int ty2 = tid >> 2;  // phase A: 2 b rows each
  const int txuB = tid & 1;  // phase B: unit
  const int tybB = tid >> 1; // phase B: 1 b row
  const int u0B = bid * 2;

  for (int t = 0; t < T_ENC + T_DEC; ++t) {
    const bool enc = t < T_ENC;

    // ================= phase A =================
    {
      const float* hsrc = isL1 ? h1r : h2r;
      float acc[3][2] = {{0.f, 0.f}, {0.f, 0.f}, {0.f, 0.f}};
      for (int k0 = 0; k0 < HID_; k0 += KC) {
#pragma unroll
        for (int i = 0; i < 4; ++i) {        // stage h chunk: 128 x 32
          int v = i * 256 + tid;
          int row = v >> 3, kq = v & 7;
          float4 hv = *reinterpret_cast<const float4*>(&hsrc[(size_t)row * HID_ + k0 + kq * 4]);
          Hs[kq * 4 + 0][row] = hv.x; Hs[kq * 4 + 1][row] = hv.y;
          Hs[kq * 4 + 2][row] = hv.z; Hs[kq * 4 + 3][row] = hv.w;
        }
        if (tid < 192) {                     // stage 12 W cols x 32 k
          int v = tid * 2;
          int e = v >> 5, kk = v & 31;
          int u = e / 3, g = e - u * 3;
          int col = isL1 ? (g * HID_ + u0A + u) : (c0A + e);
          float2 w2 = *reinterpret_cast<const float2*>(&WA[(size_t)col * HID_ + k0 + kk]);
          Ws[kk][u * 4 + g] = w2.x; Ws[kk + 1][u * 4 + g] = w2.y;
        }
        __syncthreads();
#pragma unroll
        for (int kk = 0; kk < KC; ++kk) {
          float2 hv = *reinterpret_cast<const float2*>(&Hs[kk][ty2 * 2]);
          float4 wv = *reinterpret_cast<const float4*>(&Ws[kk][txu * 4]);
          acc[0][0] += wv.x * hv.x; acc[0][1] += wv.x * hv.y;
          acc[1][0] += wv.y * hv.x; acc[1][1] += wv.y * hv.y;
          acc[2][0] += wv.z * hv.x; acc[2][1] += wv.z * hv.y;
        }
        __syncthreads();
      }
      if (isL1) {
        const float* gi1 = enc ? (G1 + (size_t)t * G3_) : b_ih1;
        const size_t gi1s = enc ? (size_t)T_ENC * G3_ : 0;
        int u = u0A + txu;
#pragma unroll
        for (int i = 0; i < 2; ++i) {
          int b = ty2 * 2 + i;
          const float* gi = gi1 + (size_t)b * gi1s;
          float r = sigmoidf_(gi[u]            + acc[0][i] + b_hh1[u]);
          float z = sigmoidf_(gi[HID_ + u]     + acc[1][i] + b_hh1[HID_ + u]);
          float hn = acc[2][i] + b_hh1[2 * HID_ + u];
          float n = tanhf(gi[2 * HID_ + u] + r * hn);
          float hp = h1r[(size_t)b * HID_ + u];
          h1w[(size_t)b * HID_ + u] = (1.f - z) * n + z * hp;
        }
      } else {
#pragma unroll
        for (int i = 0; i < 2; ++i) {
          int b = ty2 * 2 + i;
          int c = c0A + txu * 3;
          float* gr = &gh2[(size_t)b * G3_ + c];
          gr[0] = acc[0][i] + b_hh2[c + 0];
          gr[1] = acc[1][i] + b_hh2[c + 1];
          gr[2] = acc[2][i] + b_hh2[c + 2];
        }
      }
    }
    grid_barrier(bar_cnt, bar_gen);

    // ================= phase B =================
    {
      float acc[3] = {0.f, 0.f, 0.f};
      for (int k0 = 0; k0 < HID_; k0 += KC) {
#pragma unroll
        for (int i = 0; i < 4; ++i) {        // stage h1_new chunk
          int v = i * 256 + tid;
          int row = v >> 3, kq = v & 7;
          float4 hv = *reinterpret_cast<const float4*>(&h1w[(size_t)row * HID_ + k0 + kq * 4]);
          Hs[kq * 4 + 0][row] = hv.x; Hs[kq * 4 + 1][row] = hv.y;
          Hs[kq * 4 + 2][row] = hv.z; Hs[kq * 4 + 3][row] = hv.w;
        }
        if (tid < 192) {                     // stage 6 W_ih2 cols x 32 k
          int e = tid >> 5, kk = tid & 31;
          int u = e / 3, g = e - u * 3;
          int col = g * HID_ + u0B + u;
          Ws[kk][u * 4 + g] = W_ih2[(size_t)col * EMB_ + k0 + kk];
        }
        __syncthreads();
#pragma unroll
        for (int kk = 0; kk < KC; ++kk) {
          float hv = Hs[kk][tybB];
          float4 wv = *reinterpret_cast<const float4*>(&Ws[kk][txuB * 4]);
          acc[0] += wv.x * hv; acc[1] += wv.y * hv; acc[2] += wv.z * hv;
        }
        __syncthreads();
      }
      int u = u0B + txuB;
      int b = tybB;
      const float* gi2 = enc ? b_ih2
                             : (GW + (size_t)(t - T_ENC) * G3_ + (size_t)b * (T_DEC * G3_));
      float hr = gh2[(size_t)b * G3_ + u];
      float hz = gh2[(size_t)b * G3_ + HID_ + u];
      float hn = gh2[(size_t)b * G3_ + 2 * HID_ + u];
      float r = sigmoidf_(gi2[u] + acc[0] + hr);
      float z = sigmoidf_(gi2[HID_ + u] + acc[1] + hz);
      float n = tanhf(gi2[2 * HID_ + u] + acc[2] + r * hn);
      float hp = h2r[(size_t)b * HID_ + u];
      float hv2 = (1.f - z) * n + z * hp;
      h2w[(size_t)b * HID_ + u] = hv2;
      if (!enc) h2seq[((size_t)b * T_DEC + (t - T_ENC)) * HID_ + u] = hv2;
    }
    grid_barrier(bar_cnt, bar_gen);

    float* tmp = h1r; h1r = h1w; h1w = tmp;
    tmp = h2r; h2r = h2w; h2w = tmp;
  }
}

// ---------------- log-softmax over rows of 20000 (in place on d_out) ----------------
__global__ __launch_bounds__(256) void k_logsoftmax(float* __restrict__ out) {
  float* row = out + (size_t)blockIdx.x * V_;
  const int tid = threadIdx.x;
  float mx = -INFINITY, s = 0.f;
  for (int i = tid; i < V_; i += 256) {
    float x = row[i];
    if (x > mx) { s = s * expf(mx - x) + 1.f; mx = x; }
    else        { s += expf(x - mx); }
  }
#pragma unroll
  for (int o = 1; o < 64; o <<= 1) {
    float omx = __shfl_xor(mx, o);
    float os  = __shfl_xor(s, o);
    float M = fmaxf(mx, omx);
    s = s * expf(mx - M) + os * expf(omx - M);
    mx = M;
  }
  __shared__ float smx[4], ss[4];
  int wid = tid >> 6, lane = tid & 63;
  if (lane == 0) { smx[wid] = mx; ss[wid] = s; }
  __syncthreads();
  if (tid == 0) {
    float M = smx[0]; float S = ss[0];
#pragma unroll
    for (int w = 1; w < 4; ++w) {
      float M2 = fmaxf(M, smx[w]);
      S = S * expf(M - M2) + ss[w] * expf(smx[w] - M2);
      M = M2;
    }
    ss[0] = logf(S) + M;
  }
  __syncthreads();
  float lse = ss[0];
  for (int i = tid; i < V_; i += 256) row[i] -= lse;
}

// ---------------- host launch ----------------
extern "C" void kernel_launch(void* const* d_in, const int* in_sizes, int n_in,
                              void* d_out, int out_size, void* d_ws, size_t ws_size,
                              hipStream_t stream) {
  const float* input = (const float*)d_in[0];
  const int*   target = (const int*)d_in[1];
  const float* W_ih1 = (const float*)d_in[2];
  const float* W_hh1 = (const float*)d_in[3];
  const float* b_ih1 = (const float*)d_in[4];
  const float* b_hh1 = (const float*)d_in[5];
  const float* W_ih2 = (const float*)d_in[6];
  const float* W_hh2 = (const float*)d_in[7];
  const float* b_ih2 = (const float*)d_in[8];
  const float* b_hh2 = (const float*)d_in[9];
  const float* E     = (const float*)d_in[10];
  const float* W_out = (const float*)d_in[11];
  const float* b_out = (const float*)d_in[12];
  float* out = (float*)d_out;

  float* ws = (float*)d_ws;
  float* G1    = ws; ws += (size_t)B_ * T_ENC * G3_;
  float* GW    = ws; ws += (size_t)B_ * T_DEC * G3_;
  float* words = ws; ws += (size_t)B_ * T_DEC * HID_;
  float* h2seq = ws; ws += (size_t)B_ * T_DEC * HID_;
  float* h1a = ws; ws += B_ * HID_;
  float* h2a = ws; ws += B_ * HID_;      // h1a,h2a,bar contiguous -> one memset
  unsigned* bar = (unsigned*)ws; ws += 64;  // bar[0]=cnt, bar[32]=gen (separate lines)
  float* h1b = ws; ws += B_ * HID_;
  float* h2b = ws; ws += B_ * HID_;
  float* gh2 = ws; ws += (size_t)B_ * G3_;

  hipMemsetAsync(h1a, 0, ((size_t)2 * B_ * HID_) * sizeof(float) + 256, stream);

  k_gather<<<B_ * T_DEC, 128, 0, stream>>>(target, E, words);
  k_gemm<<<dim3(G3_ / 128, (B_ * T_ENC) / 128), 256, 0, stream>>>(
      input, EMB_, W_ih1, EMB_, 0, b_ih1, G1, G3_, G3_, EMB_);
  k_gemm<<<dim3(G3_ / 128, (B_ * T_DEC) / 128), 256, 0, stream>>>(
      words, HID_, W_ih2, EMB_, HID_, b_ih2, GW, G3_, G3_, HID_);

  k_recur<<<NBLK, 256, 0, stream>>>(G1, GW, W_hh1, b_hh1, W_hh2, b_hh2, W_ih2,
                                    b_ih1, b_ih2, h1a, h1b, h2a, h2b, gh2, h2seq,
                                    &bar[0], &bar[32]);

  k_gemm<<<dim3((V_ + 127) / 128, (B_ * T_DEC) / 128), 256, 0, stream>>>(
      h2seq, HID_, W_out, HID_, 0, b_out, out, V_, V_, HID_);
  k_logsoftmax<<<B_ * T_DEC, 256, 0, stream>>>(out);
}

// Round 3
// 6252.383 us; speedup vs baseline: 1.3501x; 1.3501x over previous
//
#include <hip/hip_runtime.h>
#include <math.h>

typedef float f4x __attribute__((ext_vector_type(4)));

#define B_    128
#define T_ENC 40
#define T_DEC 27
#define T_ALL 67
#define HID_  512
#define G3_   1536
#define EMB_  1024
#define V_    20000
#define NBLK  256

__device__ __forceinline__ float sigmoidf_(float x) { return 1.f / (1.f + expf(-x)); }

// ---------------- grid barrier: monotone gen, relaxed poll, 2 fences total ----------------
__device__ __forceinline__ void grid_barrier(unsigned* cnt, unsigned* gen, unsigned my_bar) {
  __syncthreads();
  if (threadIdx.x == 0) {
    __threadfence();  // release: h-slice stores visible at device scope
    if (__hip_atomic_fetch_add(cnt, 1u, __ATOMIC_RELAXED, __HIP_MEMORY_SCOPE_AGENT) == NBLK - 1u) {
      __hip_atomic_store(cnt, 0u, __ATOMIC_RELAXED, __HIP_MEMORY_SCOPE_AGENT);
      __hip_atomic_store(gen, my_bar, __ATOMIC_RELEASE, __HIP_MEMORY_SCOPE_AGENT);
    } else {
      while (__hip_atomic_load(gen, __ATOMIC_RELAXED, __HIP_MEMORY_SCOPE_AGENT) < my_bar) {
        __builtin_amdgcn_s_sleep(2);
      }
    }
    __threadfence();  // acquire: drop stale lines before reading others' h
  }
  __syncthreads();
}

// ---------------- gather decoder word embeddings ----------------
__global__ __launch_bounds__(128) void k_gather(const int* __restrict__ target,
                                                const float* __restrict__ E,
                                                float* __restrict__ words) {
  int m = blockIdx.x;
  int b = m / T_DEC, t = m % T_DEC;
  int idx = target[b * 28 + t];
  const float4* src = reinterpret_cast<const float4*>(E + (size_t)idx * HID_);
  float4* dst = reinterpret_cast<float4*>(words + (size_t)m * HID_);
  dst[threadIdx.x] = src[threadIdx.x];
}

// ---------------- fp32 GEMM, row-major C (projection) ----------------
__global__ __launch_bounds__(256) void k_gemm(const float* __restrict__ A, int lda,
                                              const float* __restrict__ Bm, int ldb, int boff,
                                              const float* __restrict__ bias,
                                              float* __restrict__ C, int ldc,
                                              int N, int K) {
  __shared__ float As[16][128];
  __shared__ float Bs[16][128];
  const int tid = threadIdx.x;
  const int m0 = blockIdx.y * 128;
  const int n0 = blockIdx.x * 128;
  const int tx = tid & 15, ty = tid >> 4;
  float acc[8][8];
#pragma unroll
  for (int i = 0; i < 8; ++i)
#pragma unroll
    for (int j = 0; j < 8; ++j) acc[i][j] = 0.f;

  for (int k0 = 0; k0 < K; k0 += 16) {
#pragma unroll
    for (int i = 0; i < 2; ++i) {
      int v = tid * 2 + i;
      int row = v >> 2;
      int kv = (v & 3) << 2;
      float4 a4 = *reinterpret_cast<const float4*>(&A[(size_t)(m0 + row) * lda + k0 + kv]);
      As[kv + 0][row] = a4.x; As[kv + 1][row] = a4.y; As[kv + 2][row] = a4.z; As[kv + 3][row] = a4.w;
      int nr = n0 + row;
      float4 b4 = make_float4(0.f, 0.f, 0.f, 0.f);
      if (nr < N) b4 = *reinterpret_cast<const float4*>(&Bm[(size_t)nr * ldb + boff + k0 + kv]);
      Bs[kv + 0][row] = b4.x; Bs[kv + 1][row] = b4.y; Bs[kv + 2][row] = b4.z; Bs[kv + 3][row] = b4.w;
    }
    __syncthreads();
#pragma unroll
    for (int kk = 0; kk < 16; ++kk) {
      float a[8], bb[8];
      *reinterpret_cast<float4*>(&a[0]) = *reinterpret_cast<const float4*>(&As[kk][ty * 8]);
      *reinterpret_cast<float4*>(&a[4]) = *reinterpret_cast<const float4*>(&As[kk][ty * 8 + 4]);
      *reinterpret_cast<float4*>(&bb[0]) = *reinterpret_cast<const float4*>(&Bs[kk][tx * 8]);
      *reinterpret_cast<float4*>(&bb[4]) = *reinterpret_cast<const float4*>(&Bs[kk][tx * 8 + 4]);
#pragma unroll
      for (int i = 0; i < 8; ++i)
#pragma unroll
        for (int j = 0; j < 8; ++j) acc[i][j] += a[i] * bb[j];
    }
    __syncthreads();
  }
#pragma unroll
  for (int i = 0; i < 8; ++i) {
    int m = m0 + ty * 8 + i;
    int n = n0 + tx * 8;
    if (n < N) {
      float* cp = &C[(size_t)m * ldc + n];
#pragma unroll
      for (int j = 0; j < 8; ++j) cp[j] = acc[i][j] + bias[n + j];
    }
  }
}

// ---------------- fp32 GEMM, transposed scatter-store: Ct[(t*1536+n)*128 + b], m = b*TT+t ----
// N fixed = 1536 (grid.x = 12), M multiple of 128.
__global__ __launch_bounds__(256) void k_gemm_t(const float* __restrict__ A, int lda,
                                                const float* __restrict__ Bm, int ldb, int boff,
                                                const float* __restrict__ bias,
                                                float* __restrict__ Ct, int TT, int K) {
  __shared__ float As[16][128];
  __shared__ float Bs[16][128];
  const int tid = threadIdx.x;
  const int m0 = blockIdx.y * 128;
  const int n0 = blockIdx.x * 128;
  const int tx = tid & 15, ty = tid >> 4;
  float acc[8][8];
#pragma unroll
  for (int i = 0; i < 8; ++i)
#pragma unroll
    for (int j = 0; j < 8; ++j) acc[i][j] = 0.f;

  for (int k0 = 0; k0 < K; k0 += 16) {
#pragma unroll
    for (int i = 0; i < 2; ++i) {
      int v = tid * 2 + i;
      int row = v >> 2;
      int kv = (v & 3) << 2;
      float4 a4 = *reinterpret_cast<const float4*>(&A[(size_t)(m0 + row) * lda + k0 + kv]);
      As[kv + 0][row] = a4.x; As[kv + 1][row] = a4.y; As[kv + 2][row] = a4.z; As[kv + 3][row] = a4.w;
      float4 b4 = *reinterpret_cast<const float4*>(&Bm[(size_t)(n0 + row) * ldb + boff + k0 + kv]);
      Bs[kv + 0][row] = b4.x; Bs[kv + 1][row] = b4.y; Bs[kv + 2][row] = b4.z; Bs[kv + 3][row] = b4.w;
    }
    __syncthreads();
#pragma unroll
    for (int kk = 0; kk < 16; ++kk) {
      float a[8], bb[8];
      *reinterpret_cast<float4*>(&a[0]) = *reinterpret_cast<const float4*>(&As[kk][ty * 8]);
      *reinterpret_cast<float4*>(&a[4]) = *reinterpret_cast<const float4*>(&As[kk][ty * 8 + 4]);
      *reinterpret_cast<float4*>(&bb[0]) = *reinterpret_cast<const float4*>(&Bs[kk][tx * 8]);
      *reinterpret_cast<float4*>(&bb[4]) = *reinterpret_cast<const float4*>(&Bs[kk][tx * 8 + 4]);
#pragma unroll
      for (int i = 0; i < 8; ++i)
#pragma unroll
        for (int j = 0; j < 8; ++j) acc[i][j] += a[i] * bb[j];
    }
    __syncthreads();
  }
#pragma unroll
  for (int i = 0; i < 8; ++i) {
    int m = m0 + ty * 8 + i;
    int b = m / TT, tt = m - b * TT;
    float* cp = &Ct[((size_t)tt * G3_ + n0 + tx * 8) * 128 + b];
#pragma unroll
    for (int j = 0; j < 8; ++j) cp[(size_t)j * 128] = acc[i][j] + bias[n0 + tx * 8 + j];
  }
}

// ---------------- staging helpers: global h [b][512] -> LDS Hs [k-chunk 64][132] ----------------
__device__ __forceinline__ void stage_loadA(f4x* pf, const float* __restrict__ src, int ch, int tid) {
#pragma unroll
  for (int i = 0; i < 8; ++i) {
    int v = i * 256 + tid;
    int b = v & 127, kq16 = v >> 7;
    pf[i] = *reinterpret_cast<const f4x*>(&src[(size_t)b * HID_ + ch * 64 + kq16 * 4]);
  }
}
__device__ __forceinline__ void stage_writeA(const f4x* pf, float* Hs, int tid) {
#pragma unroll
  for (int i = 0; i < 8; ++i) {
    int v = i * 256 + tid;
    int b = v & 127, kq16 = v >> 7;
#pragma unroll
    for (int jj = 0; jj < 4; ++jj) Hs[(kq16 * 4 + jj) * 132 + b] = pf[i][jj];
  }
}
__device__ __forceinline__ void stage_loadB(f4x* pf, const float* __restrict__ s1,
                                            const float* __restrict__ s2, int ch, int tid) {
#pragma unroll
  for (int i = 0; i < 16; ++i) {
    int v = i * 256 + tid;
    int b = v & 127;
    const float* s = (i < 8) ? s1 : s2;
    int kq16 = (v >> 7) & 15;
    pf[i] = *reinterpret_cast<const f4x*>(&s[(size_t)b * HID_ + ch * 64 + kq16 * 4]);
  }
}
__device__ __forceinline__ void stage_writeB(const f4x* pf, float* Hs1, float* Hs2, int tid) {
#pragma unroll
  for (int i = 0; i < 16; ++i) {
    int v = i * 256 + tid;
    int b = v & 127;
    float* d = (i < 8) ? Hs1 : Hs2;
    int kq16 = (v >> 7) & 15;
#pragma unroll
    for (int jj = 0; jj < 4; ++jj) d[(kq16 * 4 + jj) * 132 + b] = pf[i][jj];
  }
}

// ---------------- persistent recurrence: weights pinned in LDS, 2 barriers/step ----------------
// Block owns units {2*bid, 2*bid+1}. Phase A: h1_new = GRU1(h1,gi1). Phase B: h2_new = GRU2(h2, h1_new, gi2w).
__global__ __launch_bounds__(256, 1) void k_recur(
    const float* __restrict__ G1t, const float* __restrict__ GWt,
    const float* __restrict__ W_hh1, const float* __restrict__ W_ih2, const float* __restrict__ W_hh2,
    const float* __restrict__ b_hh1, const float* __restrict__ b_hh2,
    const float* __restrict__ b_ih1, const float* __restrict__ b_ih2,
    float* h1a, float* h1b, float* h2a, float* h2b,
    float* __restrict__ h2seq, unsigned* bar_cnt, unsigned* bar_gen) {
  __shared__ float Wlds[18 * 516];   // rows: mat*6 + g*2 + u  (mat 0=W_hh1,1=W_ih2,2=W_hh2)
  __shared__ float Hs1[64 * 132];
  __shared__ float Hs2[64 * 132];
  __shared__ float Scr[768];         // [b][u][g]
  __shared__ float Bss[24];          // [mat][g][u]: 0=b_hh1,1=b_hh2,2=b_ih1,3=b_ih2

  const int tid = threadIdx.x;
  const int bid = blockIdx.x;
  const int u0 = bid * 2;
  const int wid = tid >> 6;
  const int lane = tid & 63;
  const int kq = lane >> 2;          // 0..15: k-quad within 64-chunk
  const int cc = lane & 3;           // b-column group

  // ---- one-time: pin weights + biases in LDS ----
  for (int idx = tid; idx < 18 * 128; idx += 256) {
    int row = idx >> 7; int c4 = (idx & 127) << 2;
    int mm = row / 6, rem = row - mm * 6; int g = rem >> 1, uu = rem & 1;
    int grow = g * 512 + u0 + uu;
    const float* src = (mm == 0) ? (W_hh1 + (size_t)grow * 512 + c4)
                     : (mm == 1) ? (W_ih2 + (size_t)grow * 1024 + c4)
                                 : (W_hh2 + (size_t)grow * 512 + c4);
    *reinterpret_cast<f4x*>(&Wlds[row * 516 + c4]) = *reinterpret_cast<const f4x*>(src);
  }
  if (tid < 24) {
    int mm = tid / 6, rem = tid - mm * 6; int g = rem >> 1, uu = rem & 1;
    int grow = g * 512 + u0 + uu;
    const float* sb = (mm == 0) ? b_hh1 : (mm == 1) ? b_hh2 : (mm == 2) ? b_ih1 : b_ih2;
    Bss[tid] = sb[grow];
  }
  __syncthreads();

  float* h1r = h1a; float* h1w = h1b;
  float* h2r = h2a; float* h2w = h2b;
  unsigned barno = 0;

  for (int t = 0; t < T_ALL; ++t) {
    const bool enc = t < T_ENC;

    // ================= PHASE A: gh1 + combine -> h1_new =================
    {
      const int H = wid >> 1, uu = wid & 1;
      const int hbase = H * 64 + cc * 16;
      float acc[16][3];
#pragma unroll
      for (int i = 0; i < 16; ++i) { acc[i][0] = 0.f; acc[i][1] = 0.f; acc[i][2] = 0.f; }
      f4x pf[8];
      for (int ch = 0; ch < 8; ++ch) {
        if (ch == 0) { stage_loadA(pf, h1r, 0, tid); stage_writeA(pf, Hs1, tid); __syncthreads(); }
        if (ch < 7) stage_loadA(pf, h1r, ch + 1, tid);
        const int kb = ch * 64 + kq * 4;
        f4x w0 = *reinterpret_cast<const f4x*>(&Wlds[(0 + uu) * 516 + kb]);
        f4x w1 = *reinterpret_cast<const f4x*>(&Wlds[(2 + uu) * 516 + kb]);
        f4x w2 = *reinterpret_cast<const f4x*>(&Wlds[(4 + uu) * 516 + kb]);
#pragma unroll
        for (int jj = 0; jj < 4; ++jj) {
          const float* hp = &Hs1[(kq * 4 + jj) * 132 + hbase];
          f4x hq0 = *reinterpret_cast<const f4x*>(hp);
          f4x hq1 = *reinterpret_cast<const f4x*>(hp + 4);
          f4x hq2 = *reinterpret_cast<const f4x*>(hp + 8);
          f4x hq3 = *reinterpret_cast<const f4x*>(hp + 12);
          float a0 = w0[jj], a1 = w1[jj], a2 = w2[jj];
#pragma unroll
          for (int cp = 0; cp < 4; ++cp) {
            float h0 = hq0[cp], h1 = hq1[cp], h2 = hq2[cp], h3 = hq3[cp];
            acc[0 + cp][0] += h0 * a0;  acc[0 + cp][1] += h0 * a1;  acc[0 + cp][2] += h0 * a2;
            acc[4 + cp][0] += h1 * a0;  acc[4 + cp][1] += h1 * a1;  acc[4 + cp][2] += h1 * a2;
            acc[8 + cp][0] += h2 * a0;  acc[8 + cp][1] += h2 * a1;  acc[8 + cp][2] += h2 * a2;
            acc[12 + cp][0] += h3 * a0; acc[12 + cp][1] += h3 * a1; acc[12 + cp][2] += h3 * a2;
          }
        }
        if (ch < 7) { __syncthreads(); stage_writeA(pf, Hs1, tid); __syncthreads(); }
      }
      // butterfly k-reduction over kq lanes; lane kq keeps b = hbase + kq
      float og[3] = {0.f, 0.f, 0.f};
#pragma unroll
      for (int bi = 0; bi < 16; ++bi) {
#pragma unroll
        for (int g = 0; g < 3; ++g) {
          float s = acc[bi][g];
          s += __shfl_xor(s, 4); s += __shfl_xor(s, 8); s += __shfl_xor(s, 16); s += __shfl_xor(s, 32);
          if (kq == bi) og[g] = s;
        }
      }
      const int myb = hbase + kq;
      const int ug = u0 + uu;
      float gir, giz, gin;
      if (enc) {
        const float* gp = G1t + (size_t)t * G3_ * 128;
        gir = gp[(size_t)(0   + ug) * 128 + myb];
        giz = gp[(size_t)(512 + ug) * 128 + myb];
        gin = gp[(size_t)(1024 + ug) * 128 + myb];
      } else {
        gir = Bss[12 + uu]; giz = Bss[14 + uu]; gin = Bss[16 + uu];
      }
      float r = sigmoidf_(gir + og[0] + Bss[0 + uu]);
      float z = sigmoidf_(giz + og[1] + Bss[2 + uu]);
      float n = tanhf(gin + r * (og[2] + Bss[4 + uu]));
      float hv = (1.f - z) * n + z * h1r[(size_t)myb * HID_ + ug];
      h1w[(size_t)myb * HID_ + ug] = hv;
    }
    ++barno; grid_barrier(bar_cnt, bar_gen, barno);

    // ================= PHASE B: gi2 (mat0) + gh2 (mat1) + combine -> h2_new =================
    {
      const int uu = wid & 1, mat = wid >> 1;
      const float* HsB = mat ? Hs2 : Hs1;
      float acc[32][3];
#pragma unroll
      for (int i = 0; i < 32; ++i) { acc[i][0] = 0.f; acc[i][1] = 0.f; acc[i][2] = 0.f; }
      f4x pf[16];
      const int wr = 6 + mat * 6 + uu;
      for (int ch = 0; ch < 8; ++ch) {
        if (ch == 0) { stage_loadB(pf, h1w, h2r, 0, tid); stage_writeB(pf, Hs1, Hs2, tid); __syncthreads(); }
        if (ch < 7) stage_loadB(pf, h1w, h2r, ch + 1, tid);
        const int kb = ch * 64 + kq * 4;
        f4x w0 = *reinterpret_cast<const f4x*>(&Wlds[(wr + 0) * 516 + kb]);
        f4x w1 = *reinterpret_cast<const f4x*>(&Wlds[(wr + 2) * 516 + kb]);
        f4x w2 = *reinterpret_cast<const f4x*>(&Wlds[(wr + 4) * 516 + kb]);
#pragma unroll
        for (int jj = 0; jj < 4; ++jj) {
          const float* hp = &HsB[(kq * 4 + jj) * 132 + cc * 16];
          f4x lo0 = *reinterpret_cast<const f4x*>(hp);
          f4x lo1 = *reinterpret_cast<const f4x*>(hp + 4);
          f4x lo2 = *reinterpret_cast<const f4x*>(hp + 8);
          f4x lo3 = *reinterpret_cast<const f4x*>(hp + 12);
          f4x hi0 = *reinterpret_cast<const f4x*>(hp + 64);
          f4x hi1 = *reinterpret_cast<const f4x*>(hp + 68);
          f4x hi2 = *reinterpret_cast<const f4x*>(hp + 72);
          f4x hi3 = *reinterpret_cast<const f4x*>(hp + 76);
          float a0 = w0[jj], a1 = w1[jj], a2 = w2[jj];
#pragma unroll
          for (int cp = 0; cp < 4; ++cp) {
            float l0 = lo0[cp], l1 = lo1[cp], l2 = lo2[cp], l3 = lo3[cp];
            float m0 = hi0[cp], m1 = hi1[cp], m2 = hi2[cp], m3 = hi3[cp];
            acc[0 + cp][0]  += l0 * a0; acc[0 + cp][1]  += l0 * a1; acc[0 + cp][2]  += l0 * a2;
            acc[4 + cp][0]  += l1 * a0; acc[4 + cp][1]  += l1 * a1; acc[4 + cp][2]  += l1 * a2;
            acc[8 + cp][0]  += l2 * a0; acc[8 + cp][1]  += l2 * a1; acc[8 + cp][2]  += l2 * a2;
            acc[12 + cp][0] += l3 * a0; acc[12 + cp][1] += l3 * a1; acc[12 + cp][2] += l3 * a2;
            acc[16 + cp][0] += m0 * a0; acc[16 + cp][1] += m0 * a1; acc[16 + cp][2] += m0 * a2;
            acc[20 + cp][0] += m1 * a0; acc[20 + cp][1] += m1 * a1; acc[20 + cp][2] += m1 * a2;
            acc[24 + cp][0] += m2 * a0; acc[24 + cp][1] += m2 * a1; acc[24 + cp][2] += m2 * a2;
            acc[28 + cp][0] += m3 * a0; acc[28 + cp][1] += m3 * a1; acc[28 + cp][2] += m3 * a2;
          }
        }
        if (ch < 7) { __syncthreads(); stage_writeB(pf, Hs1, Hs2, tid); __syncthreads(); }
      }
      float o0[3] = {0.f, 0.f, 0.f}, o1[3] = {0.f, 0.f, 0.f};
#pragma unroll
      for (int bi = 0; bi < 32; ++bi) {
#pragma unroll
        for (int g = 0; g < 3; ++g) {
          float s = acc[bi][g];
          s += __shfl_xor(s, 4); s += __shfl_xor(s, 8); s += __shfl_xor(s, 16); s += __shfl_xor(s, 32);
          if (kq == (bi & 15)) { if (bi < 16) o0[g] = s; else o1[g] = s; }
        }
      }
      const int blo = cc * 16 + kq;
      const int bhi = 64 + cc * 16 + kq;
      const int ug = u0 + uu;
      if (mat == 1) {  // gh2 (+b_hh2) -> Scr
#pragma unroll
        for (int g = 0; g < 3; ++g) {
          Scr[blo * 6 + uu * 3 + g] = o0[g] + Bss[6 + g * 2 + uu];
          Scr[bhi * 6 + uu * 3 + g] = o1[g] + Bss[6 + g * 2 + uu];
        }
      }
      __syncthreads();
      if (mat == 0) {
#pragma unroll
        for (int p = 0; p < 2; ++p) {
          const int b = p ? bhi : blo;
          const float* o = p ? o1 : o0;
          float hr = Scr[b * 6 + uu * 3 + 0];
          float hz = Scr[b * 6 + uu * 3 + 1];
          float hn = Scr[b * 6 + uu * 3 + 2];
          float gr_, gz_, gn_;
          if (enc) {
            gr_ = Bss[18 + uu]; gz_ = Bss[20 + uu]; gn_ = Bss[22 + uu];
          } else {
            const float* gp = GWt + (size_t)(t - T_ENC) * G3_ * 128;
            gr_ = gp[(size_t)(0   + ug) * 128 + b];
            gz_ = gp[(size_t)(512 + ug) * 128 + b];
            gn_ = gp[(size_t)(1024 + ug) * 128 + b];
          }
          float r = sigmoidf_(gr_ + o[0] + hr);
          float z = sigmoidf_(gz_ + o[1] + hz);
          float n = tanhf(gn_ + o[2] + r * hn);
          float hv = (1.f - z) * n + z * h2r[(size_t)b * HID_ + ug];
          h2w[(size_t)b * HID_ + ug] = hv;
          if (!enc) h2seq[((size_t)b * T_DEC + (t - T_ENC)) * HID_ + ug] = hv;
        }
      }
    }
    ++barno; grid_barrier(bar_cnt, bar_gen, barno);

    float* tp = h1r; h1r = h1w; h1w = tp;
    tp = h2r; h2r = h2w; h2w = tp;
  }
}

// ---------------- log-softmax over rows of 20000 (in place on d_out) ----------------
__global__ __launch_bounds__(256) void k_logsoftmax(float* __restrict__ out) {
  float* row = out + (size_t)blockIdx.x * V_;
  const int tid = threadIdx.x;
  float mx = -INFINITY, s = 0.f;
  for (int i = tid; i < V_; i += 256) {
    float x = row[i];
    if (x > mx) { s = s * expf(mx - x) + 1.f; mx = x; }
    else        { s += expf(x - mx); }
  }
#pragma unroll
  for (int o = 1; o < 64; o <<= 1) {
    float omx = __shfl_xor(mx, o);
    float os  = __shfl_xor(s, o);
    float M = fmaxf(mx, omx);
    s = s * expf(mx - M) + os * expf(omx - M);
    mx = M;
  }
  __shared__ float smx[4], ss[4];
  int wid = tid >> 6, lane = tid & 63;
  if (lane == 0) { smx[wid] = mx; ss[wid] = s; }
  __syncthreads();
  if (tid == 0) {
    float M = smx[0]; float S = ss[0];
#pragma unroll
    for (int w = 1; w < 4; ++w) {
      float M2 = fmaxf(M, smx[w]);
      S = S * expf(M - M2) + ss[w] * expf(smx[w] - M2);
      M = M2;
    }
    ss[0] = logf(S) + M;
  }
  __syncthreads();
  float lse = ss[0];
  for (int i = tid; i < V_; i += 256) row[i] -= lse;
}

// ---------------- host launch ----------------
extern "C" void kernel_launch(void* const* d_in, const int* in_sizes, int n_in,
                              void* d_out, int out_size, void* d_ws, size_t ws_size,
                              hipStream_t stream) {
  const float* input = (const float*)d_in[0];
  const int*   target = (const int*)d_in[1];
  const float* W_ih1 = (const float*)d_in[2];
  const float* W_hh1 = (const float*)d_in[3];
  const float* b_ih1 = (const float*)d_in[4];
  const float* b_hh1 = (const float*)d_in[5];
  const float* W_ih2 = (const float*)d_in[6];
  const float* W_hh2 = (const float*)d_in[7];
  const float* b_ih2 = (const float*)d_in[8];
  const float* b_hh2 = (const float*)d_in[9];
  const float* E     = (const float*)d_in[10];
  const float* W_out = (const float*)d_in[11];
  const float* b_out = (const float*)d_in[12];
  float* out = (float*)d_out;

  float* ws = (float*)d_ws;
  float* G1t   = ws; ws += (size_t)T_ENC * G3_ * 128;   // [t][gate_row][b]
  float* GWt   = ws; ws += (size_t)T_DEC * G3_ * 128;   // [t][gate_row][b]
  float* words = ws; ws += (size_t)B_ * T_DEC * HID_;   // rows m = b*27+t
  float* h2seq = ws; ws += (size_t)B_ * T_DEC * HID_;   // [b][t][512]
  float* h1a = ws; ws += B_ * HID_;
  float* h2a = ws; ws += B_ * HID_;                     // h1a,h2a,bar contiguous -> one memset
  unsigned* bar = (unsigned*)ws; ws += 64;              // bar[0]=cnt, bar[32]=gen
  float* h1b = ws; ws += B_ * HID_;
  float* h2b = ws; ws += B_ * HID_;

  hipMemsetAsync(h1a, 0, ((size_t)2 * B_ * HID_) * sizeof(float) + 256, stream);

  k_gather<<<B_ * T_DEC, 128, 0, stream>>>(target, E, words);
  // G1t[t][gr][b] = (input @ W_ih1^T + b_ih1) transposed-scatter
  k_gemm_t<<<dim3(12, T_ENC), 256, 0, stream>>>(input, EMB_, W_ih1, EMB_, 0, b_ih1, G1t, T_ENC, EMB_);
  // GWt[t][gr][b] = (words @ W_ih2[:,512:]^T + b_ih2)
  k_gemm_t<<<dim3(12, T_DEC), 256, 0, stream>>>(words, HID_, W_ih2, EMB_, HID_, b_ih2, GWt, T_DEC, HID_);

  k_recur<<<NBLK, 256, 0, stream>>>(G1t, GWt, W_hh1, W_ih2, W_hh2, b_hh1, b_hh2, b_ih1, b_ih2,
                                    h1a, h1b, h2a, h2b, h2seq, &bar[0], &bar[32]);

  // logits = h2seq @ W_out^T + b_out -> rows m = b*27+t
  k_gemm<<<dim3((V_ + 127) / 128, (B_ * T_DEC) / 128), 256, 0, stream>>>(
      h2seq, HID_, W_out, HID_, 0, b_out, out, V_, V_, HID_);
  k_logsoftmax<<<B_ * T_DEC, 256, 0, stream>>>(out);
}

// Round 4
// 4172.762 us; speedup vs baseline: 2.0230x; 1.4984x over previous
//
#include <hip/hip_runtime.h>
#include <math.h>

typedef float f4x __attribute__((ext_vector_type(4)));

#define B_    128
#define T_ENC 40
#define T_DEC 27
#define T_ALL 67
#define HID_  512
#define G3_   1536
#define EMB_  1024
#define V_    20000
#define NBLK  256

__device__ __forceinline__ float sigmoidf_(float x) { return 1.f / (1.f + expf(-x)); }

// ---------------- tree grid barrier: 8 leaves x 32 + root, monotone counters ----------------
__device__ __forceinline__ void gbar(unsigned* bars, unsigned barno) {
  __syncthreads();
  if (threadIdx.x == 0) {
    __threadfence();  // release our h writes
    unsigned g = blockIdx.x >> 5;               // 8 groups of 32 blocks
    unsigned* leaf = bars + (size_t)g * 32;     // 128B apart
    unsigned* root = bars + 256;
    unsigned* gen  = bars + 288;
    if (__hip_atomic_fetch_add(leaf, 1u, __ATOMIC_RELAXED, __HIP_MEMORY_SCOPE_AGENT) == barno * 32u - 1u) {
      if (__hip_atomic_fetch_add(root, 1u, __ATOMIC_RELAXED, __HIP_MEMORY_SCOPE_AGENT) == barno * 8u - 1u) {
        __hip_atomic_store(gen, barno, __ATOMIC_RELEASE, __HIP_MEMORY_SCOPE_AGENT);
      }
    }
    while (__hip_atomic_load(gen, __ATOMIC_RELAXED, __HIP_MEMORY_SCOPE_AGENT) < barno) {
      __builtin_amdgcn_s_sleep(1);
    }
    __threadfence();  // acquire before reading others' h
  }
  __syncthreads();
}

// ---------------- gather decoder word embeddings ----------------
__global__ __launch_bounds__(128) void k_gather(const int* __restrict__ target,
                                                const float* __restrict__ E,
                                                float* __restrict__ words) {
  int m = blockIdx.x;
  int b = m / T_DEC, t = m % T_DEC;
  int idx = target[b * 28 + t];
  const float4* src = reinterpret_cast<const float4*>(E + (size_t)idx * HID_);
  float4* dst = reinterpret_cast<float4*>(words + (size_t)m * HID_);
  dst[threadIdx.x] = src[threadIdx.x];
}

// ---------------- fp32 GEMM, row-major C (projection) ----------------
__global__ __launch_bounds__(256) void k_gemm(const float* __restrict__ A, int lda,
                                              const float* __restrict__ Bm, int ldb, int boff,
                                              const float* __restrict__ bias,
                                              float* __restrict__ C, int ldc,
                                              int N, int K) {
  __shared__ float As[16][128];
  __shared__ float Bs[16][128];
  const int tid = threadIdx.x;
  const int m0 = blockIdx.y * 128;
  const int n0 = blockIdx.x * 128;
  const int tx = tid & 15, ty = tid >> 4;
  float acc[8][8];
#pragma unroll
  for (int i = 0; i < 8; ++i)
#pragma unroll
    for (int j = 0; j < 8; ++j) acc[i][j] = 0.f;

  for (int k0 = 0; k0 < K; k0 += 16) {
#pragma unroll
    for (int i = 0; i < 2; ++i) {
      int v = tid * 2 + i;
      int row = v >> 2;
      int kv = (v & 3) << 2;
      float4 a4 = *reinterpret_cast<const float4*>(&A[(size_t)(m0 + row) * lda + k0 + kv]);
      As[kv + 0][row] = a4.x; As[kv + 1][row] = a4.y; As[kv + 2][row] = a4.z; As[kv + 3][row] = a4.w;
      int nr = n0 + row;
      float4 b4 = make_float4(0.f, 0.f, 0.f, 0.f);
      if (nr < N) b4 = *reinterpret_cast<const float4*>(&Bm[(size_t)nr * ldb + boff + k0 + kv]);
      Bs[kv + 0][row] = b4.x; Bs[kv + 1][row] = b4.y; Bs[kv + 2][row] = b4.z; Bs[kv + 3][row] = b4.w;
    }
    __syncthreads();
#pragma unroll
    for (int kk = 0; kk < 16; ++kk) {
      float a[8], bb[8];
      *reinterpret_cast<float4*>(&a[0]) = *reinterpret_cast<const float4*>(&As[kk][ty * 8]);
      *reinterpret_cast<float4*>(&a[4]) = *reinterpret_cast<const float4*>(&As[kk][ty * 8 + 4]);
      *reinterpret_cast<float4*>(&bb[0]) = *reinterpret_cast<const float4*>(&Bs[kk][tx * 8]);
      *reinterpret_cast<float4*>(&bb[4]) = *reinterpret_cast<const float4*>(&Bs[kk][tx * 8 + 4]);
#pragma unroll
      for (int i = 0; i < 8; ++i)
#pragma unroll
        for (int j = 0; j < 8; ++j) acc[i][j] += a[i] * bb[j];
    }
    __syncthreads();
  }
#pragma unroll
  for (int i = 0; i < 8; ++i) {
    int m = m0 + ty * 8 + i;
    int n = n0 + tx * 8;
    if (n < N) {
      float* cp = &C[(size_t)m * ldc + n];
#pragma unroll
      for (int j = 0; j < 8; ++j) cp[j] = acc[i][j] + bias[n + j];
    }
  }
}

// ---------------- fp32 GEMM, transposed scatter-store: Ct[(t*1536+n)*128 + b], m = b*TT+t ----
__global__ __launch_bounds__(256) void k_gemm_t(const float* __restrict__ A, int lda,
                                                const float* __restrict__ Bm, int ldb, int boff,
                                                const float* __restrict__ bias,
                                                float* __restrict__ Ct, int TT, int K) {
  __shared__ float As[16][128];
  __shared__ float Bs[16][128];
  const int tid = threadIdx.x;
  const int m0 = blockIdx.y * 128;
  const int n0 = blockIdx.x * 128;
  const int tx = tid & 15, ty = tid >> 4;
  float acc[8][8];
#pragma unroll
  for (int i = 0; i < 8; ++i)
#pragma unroll
    for (int j = 0; j < 8; ++j) acc[i][j] = 0.f;

  for (int k0 = 0; k0 < K; k0 += 16) {
#pragma unroll
    for (int i = 0; i < 2; ++i) {
      int v = tid * 2 + i;
      int row = v >> 2;
      int kv = (v & 3) << 2;
      float4 a4 = *reinterpret_cast<const float4*>(&A[(size_t)(m0 + row) * lda + k0 + kv]);
      As[kv + 0][row] = a4.x; As[kv + 1][row] = a4.y; As[kv + 2][row] = a4.z; As[kv + 3][row] = a4.w;
      float4 b4 = *reinterpret_cast<const float4*>(&Bm[(size_t)(n0 + row) * ldb + boff + k0 + kv]);
      Bs[kv + 0][row] = b4.x; Bs[kv + 1][row] = b4.y; Bs[kv + 2][row] = b4.z; Bs[kv + 3][row] = b4.w;
    }
    __syncthreads();
#pragma unroll
    for (int kk = 0; kk < 16; ++kk) {
      float a[8], bb[8];
      *reinterpret_cast<float4*>(&a[0]) = *reinterpret_cast<const float4*>(&As[kk][ty * 8]);
      *reinterpret_cast<float4*>(&a[4]) = *reinterpret_cast<const float4*>(&As[kk][ty * 8 + 4]);
      *reinterpret_cast<float4*>(&bb[0]) = *reinterpret_cast<const float4*>(&Bs[kk][tx * 8]);
      *reinterpret_cast<float4*>(&bb[4]) = *reinterpret_cast<const float4*>(&Bs[kk][tx * 8 + 4]);
#pragma unroll
      for (int i = 0; i < 8; ++i)
#pragma unroll
        for (int j = 0; j < 8; ++j) acc[i][j] += a[i] * bb[j];
    }
    __syncthreads();
  }
#pragma unroll
  for (int i = 0; i < 8; ++i) {
    int m = m0 + ty * 8 + i;
    int b = m / TT, tt = m - b * TT;
    float* cp = &Ct[((size_t)tt * G3_ + n0 + tx * 8) * 128 + b];
#pragma unroll
    for (int j = 0; j < 8; ++j) cp[(size_t)j * 128] = acc[i][j] + bias[n0 + tx * 8 + j];
  }
}

// ---------------- persistent recurrence: merged phase (A[p+1] || B[p]), 1 barrier/step ----------------
// Block owns units {2*bid, 2*bid+1}; per phase computes gh1,gi2 (from h1[p+1]) and gh2 (from h2[p]),
// then h1[p+2] (A-combine) and h2[p+1] (B-combine).
__global__ __launch_bounds__(256, 1) void k_recur(
    const float* __restrict__ G1t, const float* __restrict__ GWt,
    const float* __restrict__ W_hh1, const float* __restrict__ W_ih2, const float* __restrict__ W_hh2,
    const float* __restrict__ b_hh1, const float* __restrict__ b_hh2,
    const float* __restrict__ b_ih1, const float* __restrict__ b_ih2,
    float* h1x, float* h1y, float* h2x, float* h2y,
    float* __restrict__ h2seq, unsigned* bars) {
  __shared__ float Wlds[18 * 516];   // rows: mat*6 + g*2 + uu  (mat 0=W_hh1, 1=W_ih2[:,:512], 2=W_hh2)
  __shared__ float Hs1[128 * 68];    // h1[p+1] chunk  [b][64k + pad4]
  __shared__ float Hs2[128 * 68];    // h2[p]   chunk

  const int tid = threadIdx.x;
  const int bid = blockIdx.x;
  const int u0 = bid * 2;
  const int wid = tid >> 6;
  const int lane = tid & 63;
  const int kq = lane & 7;           // k-slice within chunk (low bits -> coalesced gate loads)
  const int cc = lane >> 3;          // b-octet
  const int uu = wid & 1;
  const int bh = wid >> 1;           // b half (64)
  const int ug = u0 + uu;
  const int myb = bh * 64 + cc * 8 + kq;  // this lane's b after reduction

  // ---- pin weights in LDS (once) ----
  for (int idx = tid; idx < 18 * 128; idx += 256) {
    int row = idx >> 7; int c4 = (idx & 127) << 2;
    int mm = row / 6, rem = row - mm * 6; int g = rem >> 1, ur = rem & 1;
    int grow = g * HID_ + u0 + ur;
    const float* src = (mm == 0) ? (W_hh1 + (size_t)grow * HID_ + c4)
                     : (mm == 1) ? (W_ih2 + (size_t)grow * EMB_ + c4)
                                 : (W_hh2 + (size_t)grow * HID_ + c4);
    *reinterpret_cast<f4x*>(&Wlds[row * 516 + c4]) = *reinterpret_cast<const f4x*>(src);
  }
  const float bh1r = b_hh1[ug], bh1z = b_hh1[HID_ + ug], bh1n = b_hh1[2 * HID_ + ug];
  const float bh2r = b_hh2[ug], bh2z = b_hh2[HID_ + ug], bh2n = b_hh2[2 * HID_ + ug];
  const float bi1r = b_ih1[ug], bi1z = b_ih1[HID_ + ug], bi1n = b_ih1[2 * HID_ + ug];
  const float bi2r = b_ih2[ug], bi2z = b_ih2[HID_ + ug], bi2n = b_ih2[2 * HID_ + ug];

  // ---- prologue: h1[1] = GRU1(h1=0, x0): gh1 = bias only ----
  {
    float gr = G1t[(size_t)ug * 128 + myb];
    float gz = G1t[(size_t)(HID_ + ug) * 128 + myb];
    float gn = G1t[(size_t)(2 * HID_ + ug) * 128 + myb];
    float r = sigmoidf_(gr + bh1r);
    float z = sigmoidf_(gz + bh1z);
    float n = tanhf(gn + r * bh1n);
    h1x[(size_t)myb * HID_ + ug] = (1.f - z) * n;
  }
  gbar(bars, 1u);

  for (int p = 0; p < T_ALL; ++p) {
    const float* h1cur = (p & 1) ? h1y : h1x;
    float*       h1nxt = (p & 1) ? h1x : h1y;
    const float* h2cur = (p & 1) ? h2y : h2x;
    float*       h2nxt = (p & 1) ? h2x : h2y;

    // gate + h-scalar prefetch (independent of staged GEMM)
    float a_gr, a_gz, a_gn, b_xr, b_xz, b_xn;
    if (p + 1 < T_ENC) {
      const float* gp = G1t + (size_t)(p + 1) * G3_ * 128;
      a_gr = gp[(size_t)ug * 128 + myb];
      a_gz = gp[(size_t)(HID_ + ug) * 128 + myb];
      a_gn = gp[(size_t)(2 * HID_ + ug) * 128 + myb];
    } else { a_gr = bi1r; a_gz = bi1z; a_gn = bi1n; }
    if (p < T_ENC) { b_xr = bi2r; b_xz = bi2z; b_xn = bi2n; }
    else {
      const float* gp = GWt + (size_t)(p - T_ENC) * G3_ * 128;
      b_xr = gp[(size_t)ug * 128 + myb];
      b_xz = gp[(size_t)(HID_ + ug) * 128 + myb];
      b_xn = gp[(size_t)(2 * HID_ + ug) * 128 + myb];
    }
    float h1p = h1cur[(size_t)myb * HID_ + ug];
    float h2p = h2cur[(size_t)myb * HID_ + ug];

    float acc[8][3][3];
#pragma unroll
    for (int bi = 0; bi < 8; ++bi)
#pragma unroll
      for (int mm = 0; mm < 3; ++mm)
#pragma unroll
        for (int g = 0; g < 3; ++g) acc[bi][mm][g] = 0.f;

    f4x p1[8], p2[8];
    for (int ch = 0; ch < 8; ++ch) {
      if (ch == 0) {
#pragma unroll
        for (int i = 0; i < 8; ++i) {
          int v = i * 256 + tid; int b = v >> 4; int kf = v & 15;
          p1[i] = *reinterpret_cast<const f4x*>(&h1cur[(size_t)b * HID_ + kf * 4]);
          p2[i] = *reinterpret_cast<const f4x*>(&h2cur[(size_t)b * HID_ + kf * 4]);
        }
#pragma unroll
        for (int i = 0; i < 8; ++i) {
          int v = i * 256 + tid; int b = v >> 4; int kf = v & 15;
          *reinterpret_cast<f4x*>(&Hs1[b * 68 + kf * 4]) = p1[i];
          *reinterpret_cast<f4x*>(&Hs2[b * 68 + kf * 4]) = p2[i];
        }
        __syncthreads();
      }
      if (ch < 7) {  // prefetch next chunk
#pragma unroll
        for (int i = 0; i < 8; ++i) {
          int v = i * 256 + tid; int b = v >> 4; int kf = v & 15;
          p1[i] = *reinterpret_cast<const f4x*>(&h1cur[(size_t)b * HID_ + (ch + 1) * 64 + kf * 4]);
          p2[i] = *reinterpret_cast<const f4x*>(&h2cur[(size_t)b * HID_ + (ch + 1) * 64 + kf * 4]);
        }
      }
      // compute chunk ch
#pragma unroll
      for (int jj = 0; jj < 2; ++jj) {
        const int ko = kq * 8 + jj * 4;
        f4x w[9];
#pragma unroll
        for (int r9 = 0; r9 < 9; ++r9) {
          int mm = r9 / 3, g = r9 - mm * 3;
          w[r9] = *reinterpret_cast<const f4x*>(&Wlds[(mm * 6 + g * 2 + uu) * 516 + ch * 64 + ko]);
        }
#pragma unroll
        for (int bi = 0; bi < 8; ++bi) {
          const int b = bh * 64 + cc * 8 + bi;
          f4x h1v = *reinterpret_cast<const f4x*>(&Hs1[b * 68 + ko]);
          f4x h2v = *reinterpret_cast<const f4x*>(&Hs2[b * 68 + ko]);
#pragma unroll
          for (int g = 0; g < 3; ++g) {
#pragma unroll
            for (int e = 0; e < 4; ++e) {
              acc[bi][0][g] += w[g][e] * h1v[e];
              acc[bi][1][g] += w[3 + g][e] * h1v[e];
              acc[bi][2][g] += w[6 + g][e] * h2v[e];
            }
          }
        }
      }
      if (ch < 7) {
        __syncthreads();
#pragma unroll
        for (int i = 0; i < 8; ++i) {
          int v = i * 256 + tid; int b = v >> 4; int kf = v & 15;
          *reinterpret_cast<f4x*>(&Hs1[b * 68 + kf * 4]) = p1[i];
          *reinterpret_cast<f4x*>(&Hs2[b * 68 + kf * 4]) = p2[i];
        }
        __syncthreads();
      }
    }

    // butterfly k-reduction over kq lanes (masks 1,2,4); lane kq==bi keeps b = cc*8+bi
    float og[3][3];
#pragma unroll
    for (int bi = 0; bi < 8; ++bi)
#pragma unroll
      for (int mm = 0; mm < 3; ++mm)
#pragma unroll
        for (int g = 0; g < 3; ++g) {
          float s = acc[bi][mm][g];
          s += __shfl_xor(s, 1); s += __shfl_xor(s, 2); s += __shfl_xor(s, 4);
          if (kq == bi) og[mm][g] = s;
        }

    // A-combine: h1[p+2]  (t_A = p+1)
    if (p + 1 < T_ALL) {
      float r = sigmoidf_(a_gr + og[0][0] + bh1r);
      float z = sigmoidf_(a_gz + og[0][1] + bh1z);
      float n = tanhf(a_gn + r * (og[0][2] + bh1n));
      h1nxt[(size_t)myb * HID_ + ug] = (1.f - z) * n + z * h1p;
    }
    // B-combine: h2[p+1]  (t_B = p)
    {
      float r = sigmoidf_(b_xr + og[1][0] + og[2][0] + bh2r);
      float z = sigmoidf_(b_xz + og[1][1] + og[2][1] + bh2z);
      float n = tanhf(b_xn + og[1][2] + r * (og[2][2] + bh2n));
      float hv = (1.f - z) * n + z * h2p;
      h2nxt[(size_t)myb * HID_ + ug] = hv;
      if (p >= T_ENC) h2seq[((size_t)myb * T_DEC + (p - T_ENC)) * HID_ + ug] = hv;
    }

    if (p + 1 < T_ALL) gbar(bars, 2u + (unsigned)p);
  }
}

// ---------------- log-softmax over rows of 20000 (in place on d_out) ----------------
__global__ __launch_bounds__(256) void k_logsoftmax(float* __restrict__ out) {
  float* row = out + (size_t)blockIdx.x * V_;
  const int tid = threadIdx.x;
  float mx = -INFINITY, s = 0.f;
  for (int i = tid; i < V_; i += 256) {
    float x = row[i];
    if (x > mx) { s = s * expf(mx - x) + 1.f; mx = x; }
    else        { s += expf(x - mx); }
  }
#pragma unroll
  for (int o = 1; o < 64; o <<= 1) {
    float omx = __shfl_xor(mx, o);
    float os  = __shfl_xor(s, o);
    float M = fmaxf(mx, omx);
    s = s * expf(mx - M) + os * expf(omx - M);
    mx = M;
  }
  __shared__ float smx[4], ss[4];
  int wid = tid >> 6, lane = tid & 63;
  if (lane == 0) { smx[wid] = mx; ss[wid] = s; }
  __syncthreads();
  if (tid == 0) {
    float M = smx[0]; float S = ss[0];
#pragma unroll
    for (int w = 1; w < 4; ++w) {
      float M2 = fmaxf(M, smx[w]);
      S = S * expf(M - M2) + ss[w] * expf(smx[w] - M2);
      M = M2;
    }
    ss[0] = logf(S) + M;
  }
  __syncthreads();
  float lse = ss[0];
  for (int i = tid; i < V_; i += 256) row[i] -= lse;
}

// ---------------- host launch ----------------
extern "C" void kernel_launch(void* const* d_in, const int* in_sizes, int n_in,
                              void* d_out, int out_size, void* d_ws, size_t ws_size,
                              hipStream_t stream) {
  const float* input = (const float*)d_in[0];
  const int*   target = (const int*)d_in[1];
  const float* W_ih1 = (const float*)d_in[2];
  const float* W_hh1 = (const float*)d_in[3];
  const float* b_ih1 = (const float*)d_in[4];
  const float* b_hh1 = (const float*)d_in[5];
  const float* W_ih2 = (const float*)d_in[6];
  const float* W_hh2 = (const float*)d_in[7];
  const float* b_ih2 = (const float*)d_in[8];
  const float* b_hh2 = (const float*)d_in[9];
  const float* E     = (const float*)d_in[10];
  const float* W_out = (const float*)d_in[11];
  const float* b_out = (const float*)d_in[12];
  float* out = (float*)d_out;

  float* ws = (float*)d_ws;
  float* G1t   = ws; ws += (size_t)T_ENC * G3_ * 128;   // [t][gate_row][b]
  float* GWt   = ws; ws += (size_t)T_DEC * G3_ * 128;   // [t][gate_row][b]
  float* words = ws; ws += (size_t)B_ * T_DEC * HID_;   // rows m = b*27+t
  float* h2seq = ws; ws += (size_t)B_ * T_DEC * HID_;   // [b][t][512]
  float* h1x = ws; ws += B_ * HID_;
  float* h1y = ws; ws += B_ * HID_;
  float* h2x = ws; ws += B_ * HID_;                     // h2x + bars contiguous -> one memset
  unsigned* bars = (unsigned*)ws; ws += 1024;           // leaves@[g*32], root@[256], gen@[288]
  float* h2y = ws; ws += B_ * HID_;

  hipMemsetAsync(h2x, 0, (size_t)B_ * HID_ * sizeof(float) + 4096, stream);

  k_gather<<<B_ * T_DEC, 128, 0, stream>>>(target, E, words);
  k_gemm_t<<<dim3(12, T_ENC), 256, 0, stream>>>(input, EMB_, W_ih1, EMB_, 0, b_ih1, G1t, T_ENC, EMB_);
  k_gemm_t<<<dim3(12, T_DEC), 256, 0, stream>>>(words, HID_, W_ih2, EMB_, HID_, b_ih2, GWt, T_DEC, HID_);

  k_recur<<<NBLK, 256, 0, stream>>>(G1t, GWt, W_hh1, W_ih2, W_hh2, b_hh1, b_hh2, b_ih1, b_ih2,
                                    h1x, h1y, h2x, h2y, h2seq, bars);

  k_gemm<<<dim3((V_ + 127) / 128, (B_ * T_DEC) / 128), 256, 0, stream>>>(
      h2seq, HID_, W_out, HID_, 0, b_out, out, V_, V_, HID_);
  k_logsoftmax<<<B_ * T_DEC, 256, 0, stream>>>(out);
}